// Round 3
// baseline (232.218 us; speedup 1.0000x reference)
//
#include <hip/hip_runtime.h>

#define BB 4
#define LL 4096
#define DD 128

typedef __attribute__((ext_vector_type(8))) short short8;
typedef __attribute__((ext_vector_type(4))) float f32x4;

__device__ __forceinline__ unsigned short f2bf(float x) {
  union { float f; unsigned int u; } c; c.f = x;
  unsigned int r = (c.u + 0x7FFFu + ((c.u >> 16) & 1u)) >> 16;
  return (unsigned short)r;
}
__device__ __forceinline__ float bf2f(unsigned short h) {
  union { unsigned int u; float f; } c; c.u = (unsigned int)h << 16;
  return c.f;
}

// ---- fused prepass: K fp32->bf16 (same layout) + V fp32->bf16 transposed [B][D][L] ----
__global__ __launch_bounds__(256) void prep(const float* __restrict__ K,
                                            const float* __restrict__ V,
                                            unsigned short* __restrict__ Kb,
                                            unsigned short* __restrict__ Vt) {
  __shared__ unsigned short tile[64 * 132];
  int b  = blockIdx.x >> 6;
  int kt = (blockIdx.x & 63) << 6;
  int t = threadIdx.x;
  {
    int key = t >> 2, part = t & 3;
    const float* src = K + ((size_t)b * LL + kt + key) * DD + part * 32;
    unsigned short* dst = Kb + ((size_t)b * LL + kt + key) * DD + part * 32;
#pragma unroll
    for (int j = 0; j < 4; ++j) {
      float4 x = *(const float4*)(src + j * 8);
      float4 y = *(const float4*)(src + j * 8 + 4);
      union { unsigned short h[8]; uint4 v; } o;
      o.h[0] = f2bf(x.x); o.h[1] = f2bf(x.y); o.h[2] = f2bf(x.z); o.h[3] = f2bf(x.w);
      o.h[4] = f2bf(y.x); o.h[5] = f2bf(y.y); o.h[6] = f2bf(y.z); o.h[7] = f2bf(y.w);
      *(uint4*)(dst + j * 8) = o.v;
    }
  }
  int keyi = t >> 5, dim = (t & 31) * 4;
#pragma unroll
  for (int j = 0; j < 8; ++j) {
    int key = keyi + j * 8;
    float4 x = *(const float4*)(V + ((size_t)b * LL + kt + key) * DD + dim);
    uint2 pk;
    pk.x = f2bf(x.x) | ((unsigned int)f2bf(x.y) << 16);
    pk.y = f2bf(x.z) | ((unsigned int)f2bf(x.w) << 16);
    *(uint2*)(tile + key * 132 + dim) = pk;
  }
  __syncthreads();
  int k4 = (t & 15) * 4, d0 = t >> 4;
#pragma unroll
  for (int j = 0; j < 8; ++j) {
    int d = d0 + j * 16;
    uint2 pk;
    pk.x = tile[(k4 + 0) * 132 + d] | ((unsigned int)tile[(k4 + 1) * 132 + d] << 16);
    pk.y = tile[(k4 + 2) * 132 + d] | ((unsigned int)tile[(k4 + 3) * 132 + d] << 16);
    *(uint2*)(Vt + ((size_t)b * DD + d) * LL + kt + k4) = pk;
  }
}

// ---- main: wave-independent flash attention, K/V frags straight from L2 ----
// Job = (batch b, 32-row stripe p, 512-key chunk c). NO barriers in the K-loop.
// jid = blockIdx.x*4+wave; u=jid/(4*NC) -> p=127-u (heavy first); b,c from remainder.
__global__ __launch_bounds__(256, 2) void attn_fwd(const float* __restrict__ Q,
                                                   const unsigned short* __restrict__ Kb,
                                                   const unsigned short* __restrict__ Vt,
                                                   float* __restrict__ Out,
                                                   unsigned short* __restrict__ partO,
                                                   float2* __restrict__ stats,
                                                   int CT, int NC) {
  __shared__ unsigned short Ps[4][32 * 72];   // per-wave P, [row][key], pad 8

  int tid = threadIdx.x;
  int wave = tid >> 6;
  int lane = tid & 63;
  int l = lane & 15, gq = lane >> 4;

  int jid = (int)blockIdx.x * 4 + wave;
  int u = jid / (4 * NC);
  int rem = jid % (4 * NC);
  int p = 127 - u;
  int b = rem / NC;
  int c = rem % NC;

  int T = (p >> 1) + 1;                 // causal key-tile count for this stripe
  if (c * CT >= T) return;              // empty chunk
  int nIters = min(CT, T - c * CT);
  int nch = (T + CT - 1) / CT;
  int ktBase = (c * CT) << 6;
  int q0 = p << 5;
  int slot = (b * 128 + p) * NC + c;

  // Q fragments for both 16-row sub-tiles, scale*log2e folded in
  const float SC = 0.08838834764831845f * 1.4426950408889634f;
  short8 qf[2][4];
#pragma unroll
  for (int mt = 0; mt < 2; ++mt) {
    const float* qp = Q + ((size_t)b * LL + q0 + mt * 16 + l) * DD + gq * 8;
#pragma unroll
    for (int cc = 0; cc < 4; ++cc) {
      float4 x = *(const float4*)(qp + cc * 32);
      float4 y = *(const float4*)(qp + cc * 32 + 4);
      short8 f;
      f[0] = (short)f2bf(x.x * SC); f[1] = (short)f2bf(x.y * SC);
      f[2] = (short)f2bf(x.z * SC); f[3] = (short)f2bf(x.w * SC);
      f[4] = (short)f2bf(y.x * SC); f[5] = (short)f2bf(y.y * SC);
      f[6] = (short)f2bf(y.z * SC); f[7] = (short)f2bf(y.w * SC);
      qf[mt][cc] = f;
    }
  }

  f32x4 acc[2][8];
#pragma unroll
  for (int mt = 0; mt < 2; ++mt)
#pragma unroll
    for (int i = 0; i < 8; ++i) acc[mt][i] = (f32x4){0.f, 0.f, 0.f, 0.f};
  float m0[2][4], ls[2][4];
#pragma unroll
  for (int mt = 0; mt < 2; ++mt)
#pragma unroll
    for (int r = 0; r < 4; ++r) { m0[mt][r] = -1e30f; ls[mt][r] = 0.f; }

  unsigned short* Pw = Ps[wave];
  const unsigned short* kbase = Kb + (size_t)b * LL * DD + gq * 8;
  const unsigned short* vbase = Vt + ((size_t)b * DD + l) * LL + gq * 8;

  for (int it = 0; it < nIters; ++it) {
    int kt = ktBase + it * 64;

    // S = Q K^T — K frags straight from global (L2), shared by both row-tiles
    f32x4 s[2][4];
#pragma unroll
    for (int nt = 0; nt < 4; ++nt) {
      const unsigned short* kp = kbase + (size_t)(kt + nt * 16 + l) * DD;
      short8 kf[4];
#pragma unroll
      for (int cc = 0; cc < 4; ++cc) kf[cc] = *(const short8*)(kp + cc * 32);
#pragma unroll
      for (int mt = 0; mt < 2; ++mt) {
        f32x4 a = (f32x4){0.f, 0.f, 0.f, 0.f};
#pragma unroll
        for (int cc = 0; cc < 4; ++cc)
          a = __builtin_amdgcn_mfma_f32_16x16x32_bf16(qf[mt][cc], kf[cc], a, 0, 0, 0);
        s[mt][nt] = a;
      }
    }

    // causal mask (diagonal tiles only)
    if (kt + 63 > q0) {
#pragma unroll
      for (int mt = 0; mt < 2; ++mt) {
        int qr = q0 + mt * 16 + gq * 4;
#pragma unroll
        for (int nt = 0; nt < 4; ++nt) {
          int key = kt + nt * 16 + l;
#pragma unroll
          for (int r = 0; r < 4; ++r)
            if (key > qr + r) s[mt][nt][r] = -1e30f;
        }
      }
    }

    // online softmax per 16-row sub-tile
#pragma unroll
    for (int mt = 0; mt < 2; ++mt) {
      float mt_[4], al[4], rs[4];
#pragma unroll
      for (int r = 0; r < 4; ++r)
        mt_[r] = fmaxf(fmaxf(s[mt][0][r], s[mt][1][r]), fmaxf(s[mt][2][r], s[mt][3][r]));
#pragma unroll
      for (int off = 1; off < 16; off <<= 1)
#pragma unroll
        for (int r = 0; r < 4; ++r)
          mt_[r] = fmaxf(mt_[r], __shfl_xor(mt_[r], off));
#pragma unroll
      for (int r = 0; r < 4; ++r) {
        float mn = fmaxf(m0[mt][r], mt_[r]);
        al[r] = exp2f(m0[mt][r] - mn);
        m0[mt][r] = mn;
      }
#pragma unroll
      for (int nt = 0; nt < 4; ++nt)
#pragma unroll
        for (int r = 0; r < 4; ++r)
          s[mt][nt][r] = exp2f(s[mt][nt][r] - m0[mt][r]);
#pragma unroll
      for (int r = 0; r < 4; ++r)
        rs[r] = (s[mt][0][r] + s[mt][1][r]) + (s[mt][2][r] + s[mt][3][r]);
#pragma unroll
      for (int off = 1; off < 16; off <<= 1)
#pragma unroll
        for (int r = 0; r < 4; ++r)
          rs[r] += __shfl_xor(rs[r], off);
      f32x4 alv = {al[0], al[1], al[2], al[3]};
#pragma unroll
      for (int r = 0; r < 4; ++r)
        ls[mt][r] = ls[mt][r] * al[r] + rs[r];
#pragma unroll
      for (int dt = 0; dt < 8; ++dt) acc[mt][dt] *= alv;

      // P: C-layout -> wave-private LDS (lgkmcnt-ordered, no barrier)
#pragma unroll
      for (int nt = 0; nt < 4; ++nt)
#pragma unroll
        for (int r = 0; r < 4; ++r)
          Pw[(mt * 16 + gq * 4 + r) * 72 + nt * 16 + l] = f2bf(s[mt][nt][r]);
    }

    // O += P V — V frags straight from global, shared by both row-tiles
#pragma unroll
    for (int kc = 0; kc < 2; ++kc) {
      short8 pa0 = *(const short8*)(Pw + l * 72 + kc * 32 + gq * 8);
      short8 pa1 = *(const short8*)(Pw + (16 + l) * 72 + kc * 32 + gq * 8);
#pragma unroll
      for (int dt = 0; dt < 8; ++dt) {
        short8 vb = *(const short8*)(vbase + (size_t)(dt * 16) * LL + kt + kc * 32);
        acc[0][dt] = __builtin_amdgcn_mfma_f32_16x16x32_bf16(pa0, vb, acc[0][dt], 0, 0, 0);
        acc[1][dt] = __builtin_amdgcn_mfma_f32_16x16x32_bf16(pa1, vb, acc[1][dt], 0, 0, 0);
      }
    }
  }

  if (nch == 1) {
    float* op = Out + ((size_t)b * LL + q0) * DD;
#pragma unroll
    for (int mt = 0; mt < 2; ++mt) {
      float inv[4];
#pragma unroll
      for (int r = 0; r < 4; ++r) inv[r] = 1.0f / ls[mt][r];
#pragma unroll
      for (int dt = 0; dt < 8; ++dt)
#pragma unroll
        for (int r = 0; r < 4; ++r)
          op[(size_t)(mt * 16 + gq * 4 + r) * DD + dt * 16 + l] = acc[mt][dt][r] * inv[r];
    }
  } else {
    unsigned short* pp = partO + (size_t)slot * 32 * 128;
#pragma unroll
    for (int mt = 0; mt < 2; ++mt) {
#pragma unroll
      for (int dt = 0; dt < 8; ++dt)
#pragma unroll
        for (int r = 0; r < 4; ++r)
          pp[(mt * 16 + gq * 4 + r) * 128 + dt * 16 + l] = f2bf(acc[mt][dt][r]);
      if (l == 0) {
#pragma unroll
        for (int r = 0; r < 4; ++r) {
          float2 st; st.x = m0[mt][r]; st.y = ls[mt][r];
          stats[(size_t)slot * 32 + mt * 16 + gq * 4 + r] = st;
        }
      }
    }
  }
}

// ---- merge partials (stripes p>=16 when NC=8) ----
__global__ __launch_bounds__(256) void merge(const unsigned short* __restrict__ partO,
                                             const float2* __restrict__ stats,
                                             float* __restrict__ Out,
                                             int CT, int NC) {
  int b = blockIdx.x / 112;
  int p = 16 + blockIdx.x % 112;
  int T = (p >> 1) + 1;
  int nch = (T + CT - 1) / CT;
  int slot0 = (b * 128 + p) * NC;

  int tid = threadIdx.x;
  int row = tid >> 3;
  int dcol = (tid & 7) * 16;

  float m = -1e30f;
  for (int cc = 0; cc < nch; ++cc)
    m = fmaxf(m, stats[(size_t)(slot0 + cc) * 32 + row].x);
  float lsum = 0.f, w[8];
  for (int cc = 0; cc < nch; ++cc) {
    float2 st = stats[(size_t)(slot0 + cc) * 32 + row];
    w[cc] = exp2f(st.x - m);
    lsum += w[cc] * st.y;
  }
  float inv = 1.0f / lsum;

  float o[16];
#pragma unroll
  for (int j = 0; j < 16; ++j) o[j] = 0.f;
  for (int cc = 0; cc < nch; ++cc) {
    const unsigned short* pp = partO + (size_t)(slot0 + cc) * 32 * 128 + (size_t)row * 128 + dcol;
    float wc = w[cc];
#pragma unroll
    for (int j = 0; j < 16; ++j) o[j] += wc * bf2f(pp[j]);
  }
  float* op = Out + ((size_t)b * LL + (p << 5) + row) * DD + dcol;
#pragma unroll
  for (int j = 0; j < 4; ++j) {
    float4 v; v.x = o[j*4] * inv; v.y = o[j*4+1] * inv; v.z = o[j*4+2] * inv; v.w = o[j*4+3] * inv;
    *(float4*)(op + j * 4) = v;
  }
}

extern "C" void kernel_launch(void* const* d_in, const int* in_sizes, int n_in,
                              void* d_out, int out_size, void* d_ws, size_t ws_size,
                              hipStream_t stream) {
  const float* K = (const float*)d_in[0];
  const float* Q = (const float*)d_in[1];
  const float* V = (const float*)d_in[2];
  float* Out = (float*)d_out;

  const size_t convBytes = (size_t)2 * BB * LL * DD * 2;   // Kb + Vt = 8 MB
  unsigned short* Kb = (unsigned short*)d_ws;
  unsigned short* Vt = Kb + (size_t)BB * LL * DD;

  int CT = 8, NC = 8;   // 512-key chunks
  size_t slots = (size_t)BB * 128 * NC;
  size_t need = convBytes + slots * 32 * 128 * 2 + slots * 32 * 8;
  if (ws_size < need) { CT = 64; NC = 1; slots = (size_t)BB * 128; }

  unsigned short* partO = (unsigned short*)((char*)d_ws + convBytes);
  float2* stats = (float2*)((char*)d_ws + convBytes + slots * 32 * 128 * 2);

  prep<<<dim3(BB * (LL / 64)), dim3(256), 0, stream>>>(K, V, Kb, Vt);
  attn_fwd<<<dim3(128 * NC), dim3(256), 0, stream>>>(Q, Kb, Vt, Out, partO, stats, CT, NC);
  if (NC > 1)
    merge<<<dim3(BB * 112), dim3(256), 0, stream>>>(partO, stats, Out, CT, NC);
}